// Round 3
// baseline (96.210 us; speedup 1.0000x reference)
//
#include <hip/hip_runtime.h>
#include <math.h>

#define N 512
#define DIM 128
#define NORM_S 3.0f

// ws layout: sums[N] | cnts[N]  (f is never materialized)

// Fused kernel: one block per anchor i.
//   phase 0: stage x_i, labels; compute all 512 inverse row norms in LDS
//   phase 1: D_ij = 18*max(0, 1 - (x_i.x_j)*rn_i*rn_j); compact same/diff lists
//   phase 2: sum softplus(D_same - D_diff) over ns x nd; one partial per block
__global__ void __launch_bounds__(256) triplet_kernel(const float* __restrict__ x,
                                                      const int* __restrict__ labels,
                                                      float* __restrict__ sums,
                                                      float* __restrict__ cnts) {
    __shared__ float xi[DIM];
    __shared__ float rn[N];
    __shared__ int   lab[N];
    __shared__ float sameD[N];
    __shared__ float diffD[N];
    __shared__ int   nsame, ndiff;
    __shared__ float red[256];

    int i = blockIdx.x;
    int t = threadIdx.x;

    if (t < DIM) xi[t] = x[i * DIM + t];
    for (int j = t; j < N; j += 256) lab[j] = labels[j];
    if (t == 0) { nsame = 0; ndiff = 0; }

    // inverse norms: thread t handles rows t and t+256 (L2-resident reads)
    for (int j = t; j < N; j += 256) {
        const float4* xr = (const float4*)(x + j * DIM);
        float s0 = 0.0f, s1 = 0.0f, s2 = 0.0f, s3 = 0.0f;
        #pragma unroll
        for (int d = 0; d < DIM / 4; d += 4) {
            float4 a0 = xr[d + 0];
            float4 a1 = xr[d + 1];
            float4 a2 = xr[d + 2];
            float4 a3 = xr[d + 3];
            s0 += a0.x * a0.x + a0.y * a0.y + a0.z * a0.z + a0.w * a0.w;
            s1 += a1.x * a1.x + a1.y * a1.y + a1.z * a1.z + a1.w * a1.w;
            s2 += a2.x * a2.x + a2.y * a2.y + a2.z * a2.z + a2.w * a2.w;
            s3 += a3.x * a3.x + a3.y * a3.y + a3.z * a3.z + a3.w * a3.w;
        }
        rn[j] = rsqrtf((s0 + s1) + (s2 + s3));
    }
    __syncthreads();

    int li = lab[i];
    float rni = rn[i];

    for (int j = t; j < N; j += 256) {
        const float4* xr = (const float4*)(x + j * DIM);
        const float4* xb = (const float4*)xi;
        float d0 = 0.0f, d1 = 0.0f, d2 = 0.0f, d3 = 0.0f;
        #pragma unroll
        for (int d = 0; d < DIM / 4; d += 4) {
            float4 a0 = xr[d + 0], b0 = xb[d + 0];
            float4 a1 = xr[d + 1], b1 = xb[d + 1];
            float4 a2 = xr[d + 2], b2 = xb[d + 2];
            float4 a3 = xr[d + 3], b3 = xb[d + 3];
            d0 += a0.x * b0.x + a0.y * b0.y + a0.z * b0.z + a0.w * b0.w;
            d1 += a1.x * b1.x + a1.y * b1.y + a1.z * b1.z + a1.w * b1.w;
            d2 += a2.x * b2.x + a2.y * b2.y + a2.z * b2.z + a2.w * b2.w;
            d3 += a3.x * b3.x + a3.y * b3.y + a3.z * b3.z + a3.w * b3.w;
        }
        float dot = (d0 + d1) + (d2 + d3);
        // D = max(0, 18 - 2*(3/||xi||)(3/||xj||) xi.xj) = 18*max(0, 1 - dot*rn_i*rn_j)
        float D = 18.0f * fmaxf(0.0f, 1.0f - dot * rn[j] * rni);
        int lj = lab[j];
        if (lj == li) {
            if (j != i) { int p = atomicAdd(&nsame, 1); sameD[p] = D; }
        } else {
            int p = atomicAdd(&ndiff, 1); diffD[p] = D;
        }
    }
    __syncthreads();

    int ns = nsame, nd = ndiff;
    float lsum = 0.0f;
    for (int js = 0; js < ns; ++js) {
        float Dij = sameD[js];
        for (int ks = t; ks < nd; ks += 256) {
            // d in [-36,36]: expf can't overflow fp32; no stabilization needed.
            float d = Dij - diffD[ks];
            lsum += __logf(1.0f + __expf(d));
        }
    }

    red[t] = lsum;
    __syncthreads();
    #pragma unroll
    for (int s = 128; s > 0; s >>= 1) {
        if (t < s) red[t] += red[t + s];
        __syncthreads();
    }
    if (t == 0) {
        sums[i] = red[0];
        cnts[i] = (float)(ns * nd);
    }
}

// Reduce the 512 per-block partials (contention-free).
__global__ void __launch_bounds__(256) finalize_kernel(const float* __restrict__ sums,
                                                       const float* __restrict__ cnts,
                                                       float* __restrict__ out) {
    __shared__ float2 red[256];
    int t = threadIdx.x;
    float2 v;
    v.x = sums[t] + sums[t + 256];
    v.y = cnts[t] + cnts[t + 256];
    red[t] = v;
    __syncthreads();
    #pragma unroll
    for (int s = 128; s > 0; s >>= 1) {
        if (t < s) {
            red[t].x += red[t + s].x;
            red[t].y += red[t + s].y;
        }
        __syncthreads();
    }
    if (t == 0) out[0] = red[0].x / red[0].y;
}

extern "C" void kernel_launch(void* const* d_in, const int* in_sizes, int n_in,
                              void* d_out, int out_size, void* d_ws, size_t ws_size,
                              hipStream_t stream) {
    const float* x      = (const float*)d_in[0];
    const int*   labels = (const int*)d_in[1];
    float*       out    = (float*)d_out;

    float* sums = (float*)d_ws;   // 512 floats
    float* cnts = sums + N;       // 512 floats

    triplet_kernel<<<N, 256, 0, stream>>>(x, labels, sums, cnts);
    finalize_kernel<<<1, 256, 0, stream>>>(sums, cnts, out);
}

// Round 4
// 74.176 us; speedup vs baseline: 1.2970x; 1.2970x over previous
//
#include <hip/hip_runtime.h>
#include <math.h>

#define N 512
#define DIM 128
#define NORM_S 3.0f
#define TR 64            // tile rows staged in LDS per iteration
#define PADS 132         // padded row stride (floats): float4-aligned, uniform banks

// ws layout: f[N*DIM] | sums[N] | cnts[N]

// Kernel 1: f = NORM_S * x / ||x||, one wave per row, coalesced float2 loads.
__global__ void __launch_bounds__(64) normalize_kernel(const float* __restrict__ x,
                                                       float* __restrict__ f) {
    int row = blockIdx.x;
    int lane = threadIdx.x;  // 0..63
    const float2* xr = (const float2*)(x + row * DIM);
    float2 v = xr[lane];
    float s = v.x * v.x + v.y * v.y;
    #pragma unroll
    for (int off = 32; off > 0; off >>= 1) s += __shfl_xor(s, off, 64);
    float scale = NORM_S / sqrtf(s);
    float2 fv;
    fv.x = v.x * scale;
    fv.y = v.y * scale;
    ((float2*)(f + row * DIM))[lane] = fv;
}

// Kernel 2: one block per anchor i. Tiles of f staged in LDS with COALESCED
// global loads; dots computed from LDS (4 threads per row x 32 dims, f_i in
// registers); D_ij = max(0, 18 - 2 dot); same/diff compaction; softplus sum.
__global__ void __launch_bounds__(256) triplet_kernel(const float* __restrict__ f,
                                                      const int* __restrict__ labels,
                                                      float* __restrict__ sums,
                                                      float* __restrict__ cnts) {
    __shared__ float xt[TR * PADS];   // 33792 B
    __shared__ float xi[DIM];
    __shared__ int   lab[N];
    __shared__ float sameD[N];
    __shared__ float diffD[N];
    __shared__ float part[256];
    __shared__ float red[256];
    __shared__ int   nsame, ndiff;

    int i = blockIdx.x;
    int t = threadIdx.x;

    if (t < DIM) xi[t] = f[i * DIM + t];
    for (int j = t; j < N; j += 256) lab[j] = labels[j];
    if (t == 0) { nsame = 0; ndiff = 0; }
    __syncthreads();

    int li = lab[i];
    int jloc  = t & (TR - 1);      // row within tile: 0..63
    int quart = t >> 6;            // 0..3
    int dbase = quart * 32;        // this thread's 32-dim slice

    // preload f_i slice into registers (tile-invariant)
    float4 bx[8];
    {
        const float4* b = (const float4*)(xi + dbase);
        #pragma unroll
        for (int q = 0; q < 8; ++q) bx[q] = b[q];
    }

    for (int tile = 0; tile < N / TR; ++tile) {
        int base = tile * TR;
        // stage tile: TR*DIM floats = 2048 float4, 8 per thread, coalesced
        const float4* src = (const float4*)(f + base * DIM);
        #pragma unroll
        for (int k = 0; k < (TR * DIM / 4) / 256; ++k) {
            int e  = t + k * 256;
            int r  = e >> 5;       // 32 float4 per row
            int c4 = e & 31;
            float4 v = src[e];
            *((float4*)(xt + r * PADS + 4 * c4)) = v;
        }
        __syncthreads();

        // split-K dot from LDS: row jloc, dims [dbase, dbase+32)
        {
            const float4* a = (const float4*)(xt + jloc * PADS + dbase);
            float d0 = 0.0f, d1 = 0.0f;
            #pragma unroll
            for (int q = 0; q < 8; q += 2) {
                float4 a0 = a[q + 0];
                float4 a1 = a[q + 1];
                d0 += a0.x * bx[q].x + a0.y * bx[q].y + a0.z * bx[q].z + a0.w * bx[q].w;
                d1 += a1.x * bx[q + 1].x + a1.y * bx[q + 1].y + a1.z * bx[q + 1].z + a1.w * bx[q + 1].w;
            }
            part[t] = d0 + d1;
        }
        __syncthreads();

        if (t < TR) {
            float dot = part[t] + part[t + 64] + part[t + 128] + part[t + 192];
            int j = base + t;
            float D = fmaxf(0.0f, 18.0f - 2.0f * dot);
            int lj = lab[j];
            if (lj == li) {
                if (j != i) { int p = atomicAdd(&nsame, 1); sameD[p] = D; }
            } else {
                int p = atomicAdd(&ndiff, 1); diffD[p] = D;
            }
        }
        __syncthreads();   // lists/part settled before next tile overwrites
    }

    int ns = nsame, nd = ndiff;
    float lsum = 0.0f;
    for (int js = 0; js < ns; ++js) {
        float Dij = sameD[js];
        for (int ks = t; ks < nd; ks += 256) {
            // d in [-36,36]: expf can't overflow fp32; no stabilization needed.
            float d = Dij - diffD[ks];
            lsum += __logf(1.0f + __expf(d));
        }
    }

    red[t] = lsum;
    __syncthreads();
    #pragma unroll
    for (int s = 128; s > 0; s >>= 1) {
        if (t < s) red[t] += red[t + s];
        __syncthreads();
    }
    if (t == 0) {
        sums[i] = red[0];
        cnts[i] = (float)(ns * nd);
    }
}

// Kernel 3: reduce the 512 per-block partials (contention-free).
__global__ void __launch_bounds__(256) finalize_kernel(const float* __restrict__ sums,
                                                       const float* __restrict__ cnts,
                                                       float* __restrict__ out) {
    __shared__ float2 red[256];
    int t = threadIdx.x;
    float2 v;
    v.x = sums[t] + sums[t + 256];
    v.y = cnts[t] + cnts[t + 256];
    red[t] = v;
    __syncthreads();
    #pragma unroll
    for (int s = 128; s > 0; s >>= 1) {
        if (t < s) {
            red[t].x += red[t + s].x;
            red[t].y += red[t + s].y;
        }
        __syncthreads();
    }
    if (t == 0) out[0] = red[0].x / red[0].y;
}

extern "C" void kernel_launch(void* const* d_in, const int* in_sizes, int n_in,
                              void* d_out, int out_size, void* d_ws, size_t ws_size,
                              hipStream_t stream) {
    const float* x      = (const float*)d_in[0];
    const int*   labels = (const int*)d_in[1];
    float*       out    = (float*)d_out;

    float* f    = (float*)d_ws;   // 512*128 floats = 256 KB
    float* sums = f + N * DIM;    // 512 floats
    float* cnts = sums + N;       // 512 floats

    normalize_kernel<<<N, 64, 0, stream>>>(x, f);
    triplet_kernel<<<N, 256, 0, stream>>>(f, labels, sums, cnts);
    finalize_kernel<<<1, 256, 0, stream>>>(sums, cnts, out);
}